// Round 1
// baseline (168.030 us; speedup 1.0000x reference)
//
#include <hip/hip_runtime.h>

#define NT 8192
#define DM 4096
#define NE 8
#define NSLOT 16384
#define CAP 1024

// ---------------------------------------------------------------- logits GEMV
// wave = 4 tokens; lane covers dims (c*256 + lane*4 .. +3) over 16 chunks
__global__ __launch_bounds__(256) void k_logits(const float* __restrict__ x,
                                                const float* __restrict__ gw,
                                                float* __restrict__ logits) {
  const int lane = threadIdx.x & 63;
  const int wave = (blockIdx.x * blockDim.x + threadIdx.x) >> 6;  // 0..2047
  const int t0 = wave * 4;
  const float4* __restrict__ xv = (const float4*)x;
  const float4* __restrict__ gv = (const float4*)gw;

  float acc[4][8];
#pragma unroll
  for (int t = 0; t < 4; ++t)
#pragma unroll
    for (int e = 0; e < 8; ++e) acc[t][e] = 0.f;

  for (int c = 0; c < 16; ++c) {
    const int off = c * 64 + lane;
    float4 g4[8];
#pragma unroll
    for (int e = 0; e < 8; ++e) g4[e] = gv[e * (DM / 4) + off];
#pragma unroll
    for (int t = 0; t < 4; ++t) {
      const float4 xr = xv[(size_t)(t0 + t) * (DM / 4) + off];
#pragma unroll
      for (int e = 0; e < 8; ++e) {
        acc[t][e] = fmaf(xr.x, g4[e].x, acc[t][e]);
        acc[t][e] = fmaf(xr.y, g4[e].y, acc[t][e]);
        acc[t][e] = fmaf(xr.z, g4[e].z, acc[t][e]);
        acc[t][e] = fmaf(xr.w, g4[e].w, acc[t][e]);
      }
    }
  }

  float val = 0.f;
#pragma unroll
  for (int t = 0; t < 4; ++t)
#pragma unroll
    for (int e = 0; e < 8; ++e) {
      float v = acc[t][e];
#pragma unroll
      for (int s = 32; s > 0; s >>= 1) v += __shfl_xor(v, s, 64);
      if (lane == t * 8 + e) val = v;
    }
  if (lane < 32) logits[(size_t)wave * 32 + lane] = val;
}

// ---------------------------------------------------------------- routing
__global__ __launch_bounds__(256) void k_route(const float* __restrict__ logits,
                                               int* __restrict__ topk_idx,
                                               float* __restrict__ topk_p,
                                               unsigned char* __restrict__ flat_e,
                                               float* __restrict__ partials,
                                               int* __restrict__ usage) {
  const int n = blockIdx.x * blockDim.x + threadIdx.x;
  float l[8];
  const float4 a = ((const float4*)logits)[n * 2];
  const float4 b = ((const float4*)logits)[n * 2 + 1];
  l[0] = a.x; l[1] = a.y; l[2] = a.z; l[3] = a.w;
  l[4] = b.x; l[5] = b.y; l[6] = b.z; l[7] = b.w;

  float m = l[0];
#pragma unroll
  for (int e = 1; e < 8; ++e) m = fmaxf(m, l[e]);
  float ex[8];
  float s = 0.f;
#pragma unroll
  for (int e = 0; e < 8; ++e) { ex[e] = expf(l[e] - m); s += ex[e]; }
  const float lse = m + logf(s);

  // top-2 with earliest-index tie-break (strict >), no dynamic reg indexing
  float b0 = l[0]; int i0 = 0;
#pragma unroll
  for (int e = 1; e < 8; ++e) if (l[e] > b0) { b0 = l[e]; i0 = e; }
  float b1 = -3.4e38f; int i1 = 0;
#pragma unroll
  for (int e = 0; e < 8; ++e) if (e != i0 && l[e] > b1) { b1 = l[e]; i1 = e; }

  // softmax over [b0, b1] (b0 is the max), then renorm by clipped sum
  const float t1 = expf(b1 - b0);
  const float ss = 1.f + t1;
  float p0 = 1.f / ss, p1 = t1 / ss;
  float s2 = p0 + p1;
  s2 = fmaxf(s2, 1e-8f);
  p0 /= s2; p1 /= s2;

  topk_idx[2 * n] = i0; topk_idx[2 * n + 1] = i1;
  topk_p[2 * n] = p0;   topk_p[2 * n + 1] = p1;
  flat_e[2 * n] = (unsigned char)i0; flat_e[2 * n + 1] = (unsigned char)i1;

  // deterministic per-block partials: 8 expert prob-sums + sum(lse^2)
  const int lane = threadIdx.x & 63, wid = threadIdx.x >> 6;
  __shared__ float wred[4][9];
  float vals[9];
#pragma unroll
  for (int e = 0; e < 8; ++e) vals[e] = ex[e] / s;
  vals[8] = lse * lse;
#pragma unroll
  for (int r = 0; r < 9; ++r) {
    float v = vals[r];
#pragma unroll
    for (int sh = 32; sh > 0; sh >>= 1) v += __shfl_xor(v, sh, 64);
    if (lane == 0) wred[wid][r] = v;
  }
  __syncthreads();
  if (threadIdx.x < 9) {
    float acc2 = 0.f;
    for (int w = 0; w < 4; ++w) acc2 += wred[w][threadIdx.x];
    partials[blockIdx.x * 9 + threadIdx.x] = acc2;
  }
  if (blockIdx.x == 0 && threadIdx.x >= 32 && threadIdx.x < 40)
    usage[threadIdx.x - 32] = 0;
}

// ---------------------------------------------------------------- capacity rank
// rank(i) = #{ j : e_j==e_i && (p_j>p_i || (p_j==p_i && j<i)) }
__global__ __launch_bounds__(256) void k_rank(const float* __restrict__ flat_p,
                                              const unsigned char* __restrict__ flat_e,
                                              int* __restrict__ rank) {
  __shared__ float p_lds[NSLOT];          // 64 KB
  __shared__ unsigned char e_lds[NSLOT];  // 16 KB
  const int t = threadIdx.x;
  for (int i = t; i < NSLOT / 4; i += 256) {
    ((float4*)p_lds)[i] = ((const float4*)flat_p)[i];
    ((unsigned int*)e_lds)[i] = ((const unsigned int*)flat_e)[i];
  }
  __syncthreads();
  const int slot = blockIdx.x * 32 + (t & 31);
  const int part = t >> 5;  // 8 j-partitions of 2048 each
  const float pi = p_lds[slot];
  const unsigned int ei = e_lds[slot];
  int cnt = 0;
  const int jbase = part * (NSLOT / 8);
  for (int jj = 0; jj < NSLOT / 8; jj += 4) {
    const int j = jbase + jj;
    const float4 p4 = *(const float4*)&p_lds[j];
    const unsigned int e4 = *(const unsigned int*)&e_lds[j];
#pragma unroll
    for (int k = 0; k < 4; ++k) {
      const float pj = (k == 0) ? p4.x : (k == 1) ? p4.y : (k == 2) ? p4.z : p4.w;
      const unsigned int ej = (e4 >> (8 * k)) & 0xffu;
      if (ej == ei && (pj > pi || (pj == pi && (j + k) < slot))) ++cnt;
    }
  }
  __syncthreads();
  int* cred = (int*)p_lds;  // reuse LDS after all reads done
  cred[t] = cnt;
  __syncthreads();
  if (t < 32) {
    int r = 0;
#pragma unroll
    for (int q = 0; q < 8; ++q) r += cred[q * 32 + t];
    rank[blockIdx.x * 32 + t] = r;
  }
}

// ---------------------------------------------------------------- finalize
__global__ __launch_bounds__(256) void k_final(const int* __restrict__ topk_idx,
                                               const float* __restrict__ topk_p,
                                               const int* __restrict__ rank,
                                               float* __restrict__ out,
                                               int* __restrict__ usage) {
  const int n = blockIdx.x * blockDim.x + threadIdx.x;
  const int i0 = topk_idx[2 * n], i1 = topk_idx[2 * n + 1];
  const float p0 = topk_p[2 * n], p1 = topk_p[2 * n + 1];
  const bool k0 = rank[2 * n] < CAP, k1 = rank[2 * n + 1] < CAP;
  out[2 * n]     = k0 ? (float)i0 : -1.0f;
  out[2 * n + 1] = k1 ? (float)i1 : -1.0f;
  out[NSLOT + 2 * n]     = k0 ? p0 : 0.0f;
  out[NSLOT + 2 * n + 1] = k1 ? p1 : 0.0f;
  if (k0) atomicAdd(&usage[i0], 1);  // one_hot(top1) only when kept
}

__global__ __launch_bounds__(64) void k_loss(const float* __restrict__ partials,
                                             const int* __restrict__ usage,
                                             float* __restrict__ out) {
  __shared__ float ps[9];
  const int t = threadIdx.x;
  if (t < 9) {
    float a = 0.f;
    for (int b = 0; b < 32; ++b) a += partials[b * 9 + t];
    ps[t] = a;
  }
  __syncthreads();
  if (t == 0) {
    float lb = 0.f;
    for (int e = 0; e < 8; ++e) lb += ps[e] * (float)usage[e];
    out[2 * NSLOT]     = lb * (0.01f / (float)(NT * NE));
    out[2 * NSLOT + 1] = (ps[8] / (float)NT) * 0.001f;
  }
  if (t < 8) out[2 * NSLOT + 2 + t] = (float)usage[t];
}

extern "C" void kernel_launch(void* const* d_in, const int* in_sizes, int n_in,
                              void* d_out, int out_size, void* d_ws, size_t ws_size,
                              hipStream_t stream) {
  const float* x  = (const float*)d_in[0];
  const float* gw = (const float*)d_in[1];
  float* out = (float*)d_out;
  char* ws = (char*)d_ws;

  float* logits         = (float*)(ws);                    // 262144 B
  int* topk_idx         = (int*)(ws + 262144);             // 65536 B
  float* topk_p         = (float*)(ws + 327680);           // 65536 B
  unsigned char* flat_e = (unsigned char*)(ws + 393216);   // 16384 B
  int* rankbuf          = (int*)(ws + 409600);             // 65536 B
  float* partials       = (float*)(ws + 475136);           // 1152 B
  int* usage            = (int*)(ws + 476288);             // 32 B

  hipLaunchKernelGGL(k_logits, dim3(512), dim3(256), 0, stream, x, gw, logits);
  hipLaunchKernelGGL(k_route, dim3(32), dim3(256), 0, stream, logits, topk_idx,
                     topk_p, flat_e, partials, usage);
  hipLaunchKernelGGL(k_rank, dim3(512), dim3(256), 0, stream, topk_p, flat_e, rankbuf);
  hipLaunchKernelGGL(k_final, dim3(32), dim3(256), 0, stream, topk_idx, topk_p,
                     rankbuf, out, usage);
  hipLaunchKernelGGL(k_loss, dim3(1), dim3(64), 0, stream, partials, usage, out);
}

// Round 2
// 127.593 us; speedup vs baseline: 1.3169x; 1.3169x over previous
//
#include <hip/hip_runtime.h>

#define NT 8192
#define DM 4096
#define NE 8
#define NSLOT 16384
#define CAP 1024
#define BMAX 8192  // boundary-bucket compaction capacity (64 KB LDS)

// ---------------------------------------------------------------- logits GEMV
// wave = 4 tokens; lane covers dims (c*256 + lane*4 .. +3) over 16 chunks
__global__ __launch_bounds__(256) void k_logits(const float* __restrict__ x,
                                                const float* __restrict__ gw,
                                                float* __restrict__ logits) {
  const int lane = threadIdx.x & 63;
  const int wave = (blockIdx.x * blockDim.x + threadIdx.x) >> 6;  // 0..2047
  const int t0 = wave * 4;
  const float4* __restrict__ xv = (const float4*)x;
  const float4* __restrict__ gv = (const float4*)gw;

  float acc[4][8];
#pragma unroll
  for (int t = 0; t < 4; ++t)
#pragma unroll
    for (int e = 0; e < 8; ++e) acc[t][e] = 0.f;

  for (int c = 0; c < 16; ++c) {
    const int off = c * 64 + lane;
    float4 g4[8];
#pragma unroll
    for (int e = 0; e < 8; ++e) g4[e] = gv[e * (DM / 4) + off];
#pragma unroll
    for (int t = 0; t < 4; ++t) {
      const float4 xr = xv[(size_t)(t0 + t) * (DM / 4) + off];
#pragma unroll
      for (int e = 0; e < 8; ++e) {
        acc[t][e] = fmaf(xr.x, g4[e].x, acc[t][e]);
        acc[t][e] = fmaf(xr.y, g4[e].y, acc[t][e]);
        acc[t][e] = fmaf(xr.z, g4[e].z, acc[t][e]);
        acc[t][e] = fmaf(xr.w, g4[e].w, acc[t][e]);
      }
    }
  }

  float val = 0.f;
#pragma unroll
  for (int t = 0; t < 4; ++t)
#pragma unroll
    for (int e = 0; e < 8; ++e) {
      float v = acc[t][e];
#pragma unroll
      for (int s = 32; s > 0; s >>= 1) v += __shfl_xor(v, s, 64);
      if (lane == t * 8 + e) val = v;
    }
  if (lane < 32) logits[(size_t)wave * 32 + lane] = val;
}

// ---------------------------------------------------------------- routing
__global__ __launch_bounds__(256) void k_route(const float* __restrict__ logits,
                                               int* __restrict__ topk_idx,
                                               float* __restrict__ topk_p,
                                               unsigned char* __restrict__ flat_e,
                                               float* __restrict__ partials,
                                               int* __restrict__ usage) {
  const int n = blockIdx.x * blockDim.x + threadIdx.x;
  float l[8];
  const float4 a = ((const float4*)logits)[n * 2];
  const float4 b = ((const float4*)logits)[n * 2 + 1];
  l[0] = a.x; l[1] = a.y; l[2] = a.z; l[3] = a.w;
  l[4] = b.x; l[5] = b.y; l[6] = b.z; l[7] = b.w;

  float m = l[0];
#pragma unroll
  for (int e = 1; e < 8; ++e) m = fmaxf(m, l[e]);
  float ex[8];
  float s = 0.f;
#pragma unroll
  for (int e = 0; e < 8; ++e) { ex[e] = expf(l[e] - m); s += ex[e]; }
  const float lse = m + logf(s);

  // top-2 with earliest-index tie-break (strict >)
  float b0 = l[0]; int i0 = 0;
#pragma unroll
  for (int e = 1; e < 8; ++e) if (l[e] > b0) { b0 = l[e]; i0 = e; }
  float b1 = -3.4e38f; int i1 = 0;
#pragma unroll
  for (int e = 0; e < 8; ++e) if (e != i0 && l[e] > b1) { b1 = l[e]; i1 = e; }

  const float t1 = expf(b1 - b0);
  const float ss = 1.f + t1;
  float p0 = 1.f / ss, p1 = t1 / ss;
  float s2 = p0 + p1;
  s2 = fmaxf(s2, 1e-8f);
  p0 /= s2; p1 /= s2;

  topk_idx[2 * n] = i0; topk_idx[2 * n + 1] = i1;
  topk_p[2 * n] = p0;   topk_p[2 * n + 1] = p1;
  flat_e[2 * n] = (unsigned char)i0; flat_e[2 * n + 1] = (unsigned char)i1;

  // deterministic per-block partials: 8 expert prob-sums + sum(lse^2)
  const int lane = threadIdx.x & 63, wid = threadIdx.x >> 6;
  __shared__ float wred[4][9];
  float vals[9];
#pragma unroll
  for (int e = 0; e < 8; ++e) vals[e] = ex[e] / s;
  vals[8] = lse * lse;
#pragma unroll
  for (int r = 0; r < 9; ++r) {
    float v = vals[r];
#pragma unroll
    for (int sh = 32; sh > 0; sh >>= 1) v += __shfl_xor(v, sh, 64);
    if (lane == 0) wred[wid][r] = v;
  }
  __syncthreads();
  if (threadIdx.x < 9) {
    float acc2 = 0.f;
    for (int w = 0; w < 4; ++w) acc2 += wred[w][threadIdx.x];
    partials[blockIdx.x * 9 + threadIdx.x] = acc2;
  }
  if (blockIdx.x == 0 && threadIdx.x >= 32 && threadIdx.x < 40)
    usage[threadIdx.x - 32] = 0;
}

// ---------------------------------------------------------------- capacity select
// One block per expert. Finds the per-expert threshold key (u_thr, idx_thr)
// such that keep(slot) == (u > u_thr) || (u == u_thr && idx <= idx_thr),
// exactly equivalent to rank<CAP under ordering (p desc, idx asc).
__global__ __launch_bounds__(256) void k_select(const float* __restrict__ flat_p,
                                                const unsigned char* __restrict__ flat_e,
                                                unsigned int* __restrict__ thr_u,
                                                int* __restrict__ thr_idx) {
  const int e = blockIdx.x;
  const int t = threadIdx.x;
  __shared__ int hist[1024];
  __shared__ int ssum[256];
  __shared__ unsigned long long bkeys[BMAX];  // (u<<32) | (0xFFFFFFFF - idx)
  __shared__ int bcnt;
  __shared__ int s_bstar, s_R, s_keepall;

  for (int i = t; i < 1024; i += 256) hist[i] = 0;
  if (t == 0) { bcnt = 0; s_keepall = 0; s_bstar = -1; }
  __syncthreads();

  // 1) histogram of u>>20 (p in [0,~2) -> bucket < 1024)
  for (int i = t; i < NSLOT; i += 256) {
    if (flat_e[i] == (unsigned char)e) {
      unsigned int u = __float_as_uint(flat_p[i]);
      atomicAdd(&hist[u >> 20], 1);
    }
  }
  __syncthreads();

  // 2) suffix scan; thread t owns buckets [4t..4t+3]
  int c[4];
#pragma unroll
  for (int k = 0; k < 4; ++k) c[k] = hist[4 * t + k];
  int chunk = c[0] + c[1] + c[2] + c[3];
  ssum[t] = chunk;
  __syncthreads();
  for (int off = 1; off < 256; off <<= 1) {
    int v = ssum[t] + ((t + off < 256) ? ssum[t + off] : 0);
    __syncthreads();
    ssum[t] = v;
    __syncthreads();
  }
  const int total = ssum[0];
  if (total < CAP) {
    if (t == 0) { thr_u[e] = 0u; thr_idx[e] = 0x7FFFFFFF; s_keepall = 1; }
  } else {
    const int after = (t < 255) ? ssum[t + 1] : 0;  // count in buckets > 4t+3
    if (after < CAP && after + chunk >= CAP) {
      int sexcl = after;
#pragma unroll
      for (int k = 3; k >= 0; --k) {
        if (s_bstar < 0 && sexcl < CAP && sexcl + c[k] >= CAP) {
          s_bstar = 4 * t + k;
          s_R = CAP - sexcl;  // >= 1
        }
        sexcl += c[k];
      }
    }
  }
  __syncthreads();
  if (s_keepall) return;
  const int bstar = s_bstar, R = s_R;

  // 3) compact boundary-bucket items
  for (int i = t; i < NSLOT; i += 256) {
    if (flat_e[i] == (unsigned char)e) {
      unsigned int u = __float_as_uint(flat_p[i]);
      if ((int)(u >> 20) == bstar) {
        int pos = atomicAdd(&bcnt, 1);
        if (pos < BMAX)
          bkeys[pos] = ((unsigned long long)u << 32) | (unsigned)(0xFFFFFFFFu - (unsigned)i);
      }
    }
  }
  __syncthreads();
  const int B = bcnt;

  if (B <= BMAX) {
    // 4) exact rank among boundary items; rank R-1 is the last kept key
    for (int k = t; k < B; k += 256) {
      const unsigned long long kk = bkeys[k];
      int r = 0;
      for (int m = 0; m < B; ++m) r += (bkeys[m] > kk);
      if (r == R - 1) {
        thr_u[e] = (unsigned int)(kk >> 32);
        thr_idx[e] = (int)(0xFFFFFFFFu - (unsigned int)kk);
      }
    }
  } else {
    // fallback (never expected): O(N*B) exact rank via global memory
    for (int i = t; i < NSLOT; i += 256) {
      if (flat_e[i] != (unsigned char)e) continue;
      unsigned int ui = __float_as_uint(flat_p[i]);
      if ((int)(ui >> 20) != bstar) continue;
      int r = 0;
      for (int j = 0; j < NSLOT; ++j) {
        if (flat_e[j] != (unsigned char)e) continue;
        unsigned int uj = __float_as_uint(flat_p[j]);
        if ((int)(uj >> 20) != bstar) continue;
        if (uj > ui || (uj == ui && j < i)) ++r;
      }
      if (r == R - 1) { thr_u[e] = ui; thr_idx[e] = i; }
    }
  }
}

// ---------------------------------------------------------------- finalize
__global__ __launch_bounds__(256) void k_final(const int* __restrict__ topk_idx,
                                               const float* __restrict__ topk_p,
                                               const unsigned int* __restrict__ thr_u,
                                               const int* __restrict__ thr_idx,
                                               float* __restrict__ out,
                                               int* __restrict__ usage) {
  const int n = blockIdx.x * blockDim.x + threadIdx.x;
  const int i0 = topk_idx[2 * n], i1 = topk_idx[2 * n + 1];
  const float p0 = topk_p[2 * n], p1 = topk_p[2 * n + 1];
  const unsigned int u0 = __float_as_uint(p0), u1 = __float_as_uint(p1);
  const unsigned int tu0 = thr_u[i0], tu1 = thr_u[i1];
  const int ti0 = thr_idx[i0], ti1 = thr_idx[i1];
  const bool k0 = (u0 > tu0) || (u0 == tu0 && (2 * n) <= ti0);
  const bool k1 = (u1 > tu1) || (u1 == tu1 && (2 * n + 1) <= ti1);
  out[2 * n]     = k0 ? (float)i0 : -1.0f;
  out[2 * n + 1] = k1 ? (float)i1 : -1.0f;
  out[NSLOT + 2 * n]     = k0 ? p0 : 0.0f;
  out[NSLOT + 2 * n + 1] = k1 ? p1 : 0.0f;
  if (k0) atomicAdd(&usage[i0], 1);
}

__global__ __launch_bounds__(64) void k_loss(const float* __restrict__ partials,
                                             const int* __restrict__ usage,
                                             float* __restrict__ out) {
  __shared__ float ps[9];
  const int t = threadIdx.x;
  if (t < 9) {
    float a = 0.f;
    for (int b = 0; b < 32; ++b) a += partials[b * 9 + t];
    ps[t] = a;
  }
  __syncthreads();
  if (t == 0) {
    float lb = 0.f;
    for (int e = 0; e < 8; ++e) lb += ps[e] * (float)usage[e];
    out[2 * NSLOT]     = lb * (0.01f / (float)(NT * NE));
    out[2 * NSLOT + 1] = (ps[8] / (float)NT) * 0.001f;
  }
  if (t < 8) out[2 * NSLOT + 2 + t] = (float)usage[t];
}

extern "C" void kernel_launch(void* const* d_in, const int* in_sizes, int n_in,
                              void* d_out, int out_size, void* d_ws, size_t ws_size,
                              hipStream_t stream) {
  const float* x  = (const float*)d_in[0];
  const float* gw = (const float*)d_in[1];
  float* out = (float*)d_out;
  char* ws = (char*)d_ws;

  float* logits         = (float*)(ws);                    // 262144 B
  int* topk_idx         = (int*)(ws + 262144);             // 65536 B
  float* topk_p         = (float*)(ws + 327680);           // 65536 B
  unsigned char* flat_e = (unsigned char*)(ws + 393216);   // 16384 B
  unsigned int* thr_u   = (unsigned int*)(ws + 409600);    // 32 B
  int* thr_idx          = (int*)(ws + 409728);             // 32 B
  float* partials       = (float*)(ws + 475136);           // 1152 B
  int* usage            = (int*)(ws + 476288);             // 32 B

  hipLaunchKernelGGL(k_logits, dim3(512), dim3(256), 0, stream, x, gw, logits);
  hipLaunchKernelGGL(k_route, dim3(32), dim3(256), 0, stream, logits, topk_idx,
                     topk_p, flat_e, partials, usage);
  hipLaunchKernelGGL(k_select, dim3(8), dim3(256), 0, stream, topk_p, flat_e,
                     thr_u, thr_idx);
  hipLaunchKernelGGL(k_final, dim3(32), dim3(256), 0, stream, topk_idx, topk_p,
                     thr_u, thr_idx, out, usage);
  hipLaunchKernelGGL(k_loss, dim3(1), dim3(64), 0, stream, partials, usage, out);
}